// Round 18
// baseline (141.860 us; speedup 1.0000x reference)
//
#include <hip/hip_runtime.h>

#define S_LEN 2304   // 48*48
#define CDIM  512
#define NHEAD 8

typedef __attribute__((ext_vector_type(4)))  float f32x4;
typedef __attribute__((ext_vector_type(16))) float f32x16;
typedef __attribute__((ext_vector_type(8)))  _Float16 f16x8;
typedef __attribute__((ext_vector_type(2)))  __fp16 fp16x2r;  // cvt_pkrtz native type
typedef _Float16 h16;

// softmax runs in exp2 domain: q pre-scaled by 1/sqrt(64) * log2(e)
#define QSCALE 0.18033688011112042f

__device__ __forceinline__ float fexp2(float x) {
#if __has_builtin(__builtin_amdgcn_exp2f)
    return __builtin_amdgcn_exp2f(x);
#else
    return exp2f(x);
#endif
}

__device__ __forceinline__ unsigned cvtpk(float a, float b) {
    union { fp16x2r v; unsigned u; } c;
    c.v = __builtin_amdgcn_cvt_pkrtz(a, b);
    return c.u;
}

// async global->LDS, 16B per lane; LDS dest = wave-uniform base + lane*16
__device__ __forceinline__ void gll16(const h16* g, h16* l) {
    __builtin_amdgcn_global_load_lds(
        (const __attribute__((address_space(1))) unsigned int*)g,
        (__attribute__((address_space(3))) unsigned int*)l, 16, 0, 0);
}

// ---------------------------------------------------------------------------
// Kernel 0: fused prep. blocks [0,1152): transpose x -> xT fp16;
//           blocks [1152,2176): convert Wqkv/Wout fp32 -> fp16.
// ---------------------------------------------------------------------------
__global__ __launch_bounds__(256) void prep(
    const float* __restrict__ x, h16* __restrict__ xT,
    const float* __restrict__ Wq, const float* __restrict__ Wo,
    h16* __restrict__ Wq_h, h16* __restrict__ Wo_h)
{
    const int bid = blockIdx.x;
    if (bid >= 1152) {
        const int NQ = 1536 * 512;
        const int NO = 512 * 512;
        int i = ((bid - 1152) * 256 + threadIdx.x) * 4;
        if (i >= NQ + NO) return;
        float4 v;
        h16* dst;
        if (i < NQ) { v = *(const float4*)(Wq + i);        dst = Wq_h + i; }
        else        { v = *(const float4*)(Wo + (i - NQ)); dst = Wo_h + (i - NQ); }
        union { h16 h[4]; uint2 u; } pk;
        pk.h[0]=(h16)v.x; pk.h[1]=(h16)v.y; pk.h[2]=(h16)v.z; pk.h[3]=(h16)v.w;
        *(uint2*)dst = pk.u;
        return;
    }
    const int s0 = (bid % 36) * 64;
    const int c0 = ((bid / 36) & 7) * 64;
    const int b  = bid / 288;
    __shared__ h16 Ts[64][76];

    const int t  = threadIdx.x;
    const int cq = t >> 4;
    const int sq = t & 15;

    const float* xb = x + ((size_t)b * CDIM + c0 + cq * 4) * S_LEN + s0 + sq * 4;
    float4 r0 = *(const float4*)(xb);
    float4 r1 = *(const float4*)(xb + S_LEN);
    float4 r2 = *(const float4*)(xb + 2 * S_LEN);
    float4 r3 = *(const float4*)(xb + 3 * S_LEN);

    union { h16 h[4]; uint2 u; } pk;
    pk.h[0]=(h16)r0.x; pk.h[1]=(h16)r1.x; pk.h[2]=(h16)r2.x; pk.h[3]=(h16)r3.x;
    *(uint2*)&Ts[sq*4+0][cq*4] = pk.u;
    pk.h[0]=(h16)r0.y; pk.h[1]=(h16)r1.y; pk.h[2]=(h16)r2.y; pk.h[3]=(h16)r3.y;
    *(uint2*)&Ts[sq*4+1][cq*4] = pk.u;
    pk.h[0]=(h16)r0.z; pk.h[1]=(h16)r1.z; pk.h[2]=(h16)r2.z; pk.h[3]=(h16)r3.z;
    *(uint2*)&Ts[sq*4+2][cq*4] = pk.u;
    pk.h[0]=(h16)r0.w; pk.h[1]=(h16)r1.w; pk.h[2]=(h16)r2.w; pk.h[3]=(h16)r3.w;
    *(uint2*)&Ts[sq*4+3][cq*4] = pk.u;

    __syncthreads();
    const int s  = t >> 2;
    const int cc = (t & 3) * 16;
    uint2 a0 = *(uint2*)&Ts[s][cc + 0];
    uint2 a1 = *(uint2*)&Ts[s][cc + 4];
    uint2 a2 = *(uint2*)&Ts[s][cc + 8];
    uint2 a3 = *(uint2*)&Ts[s][cc + 12];
    h16* dst = xT + ((size_t)b * S_LEN + s0 + s) * CDIM + c0 + cc;
    uint4 w0 = make_uint4(a0.x, a0.y, a1.x, a1.y);
    uint4 w1 = make_uint4(a2.x, a2.y, a3.x, a3.y);
    *(uint4*)dst       = w0;
    *(uint4*)(dst + 8) = w1;
}

// ---------------------------------------------------------------------------
// Kernel 1: QKV projection, fp16 MFMA. q rows get *QSCALE (softmax exp2 domain).
// ---------------------------------------------------------------------------
__global__ __launch_bounds__(256) void gemm_qkv(
    const h16* __restrict__ Wh, const float* __restrict__ bqkv,
    const h16* __restrict__ xT, h16* __restrict__ qT, h16* __restrict__ kT,
    h16* __restrict__ vN)
{
    const int n0 = blockIdx.x * 128;
    const int m0 = blockIdx.y * 128;
    const int b  = blockIdx.z;
    __shared__ h16 Ws[128 * 64];
    __shared__ h16 Xs[128 * 64];

    const int tid = threadIdx.x;
    const int lid = tid & 63, w = tid >> 6;
    const int g = lid >> 4, ln = lid & 15;
    const int wm = w & 1, wn = w >> 1;
    const int srow = lid >> 3;
    const int sblk = (lid & 7) ^ (srow & 7);

    f32x4 acc[4][4];
#pragma unroll
    for (int i = 0; i < 4; i++)
#pragma unroll
        for (int j = 0; j < 4; j++) acc[i][j] = (f32x4)0.f;

    const h16* Wbase = Wh + (size_t)m0 * CDIM;
    const h16* Xbase = xT + ((size_t)b * S_LEN + n0) * CDIM;
    const bool vblk = (m0 >= 1024);

    for (int kt = 0; kt < CDIM; kt += 64) {
        __syncthreads();
#pragma unroll
        for (int i = 0; i < 4; i++) {
            const int row0 = w * 32 + i * 8;
            gll16(Wbase + (size_t)(row0 + srow) * CDIM + kt + sblk * 8, &Ws[row0 * 64]);
            gll16(Xbase + (size_t)(row0 + srow) * CDIM + kt + sblk * 8, &Xs[row0 * 64]);
        }
        __syncthreads();

#pragma unroll
        for (int kc = 0; kc < 2; kc++) {
            f16x8 af[4], bf[4];
#pragma unroll
            for (int i = 0; i < 4; i++) {
                const int ra = wm * 64 + i * 16 + ln;
                const int ca = (kc * 64 + g * 16) ^ ((ra & 7) << 4);
                af[i] = *(const f16x8*)&Ws[ra * 64 + ca / 2];
                const int rb = wn * 64 + i * 16 + ln;
                const int cb = (kc * 64 + g * 16) ^ ((rb & 7) << 4);
                bf[i] = *(const f16x8*)&Xs[rb * 64 + cb / 2];
            }
            if (!vblk) {
#pragma unroll
                for (int i = 0; i < 4; i++)
#pragma unroll
                    for (int j = 0; j < 4; j++)
                        acc[i][j] = __builtin_amdgcn_mfma_f32_16x16x32_f16(
                            af[i], bf[j], acc[i][j], 0, 0, 0);
            } else {
#pragma unroll
                for (int i = 0; i < 4; i++)
#pragma unroll
                    for (int j = 0; j < 4; j++)
                        acc[i][j] = __builtin_amdgcn_mfma_f32_16x16x32_f16(
                            bf[i], af[j], acc[i][j], 0, 0, 0);
            }
        }
    }

    if (!vblk) {
#pragma unroll
        for (int i = 0; i < 4; i++) {
            const int mb = m0 + wm * 64 + i * 16 + 4 * g;
            const float4 bv = *(const float4*)&bqkv[mb];
            const int mloc = mb & 511;
            const int hh = mloc >> 6, d0 = mloc & 63;
            const bool isq = (mb < 512);
            const float scl = isq ? QSCALE : 1.0f;
            h16* base = (isq ? qT : kT);
#pragma unroll
            for (int j = 0; j < 4; j++) {
                const int n = n0 + wn * 64 + j * 16 + ln;
                union { h16 h[4]; uint2 u; } pk;
                pk.h[0] = (h16)((acc[i][j][0] + bv.x) * scl);
                pk.h[1] = (h16)((acc[i][j][1] + bv.y) * scl);
                pk.h[2] = (h16)((acc[i][j][2] + bv.z) * scl);
                pk.h[3] = (h16)((acc[i][j][3] + bv.w) * scl);
                *(uint2*)(base + (((size_t)b * 8 + hh) * S_LEN + n) * 64 + d0) = pk.u;
            }
        }
    } else {
#pragma unroll
        for (int j = 0; j < 4; j++) {
            const int m = m0 + wm * 64 + j * 16 + ln;
            const float bias = bqkv[m];
            const int mloc = m - 1024;
            const int hh = mloc >> 6, d = mloc & 63;
            h16* base = vN + (((size_t)b * 8 + hh) * 64 + d) * S_LEN;
#pragma unroll
            for (int i = 0; i < 4; i++) {
                const int nb = n0 + wn * 64 + i * 16 + 4 * g;
                union { h16 h[4]; uint2 u; } pk;
                pk.h[0] = (h16)(acc[i][j][0] + bias);
                pk.h[1] = (h16)(acc[i][j][1] + bias);
                pk.h[2] = (h16)(acc[i][j][2] + bias);
                pk.h[3] = (h16)(acc[i][j][3] + bias);
                *(uint2*)(base + nb) = pk.u;
            }
        }
    }
}

// ---------------------------------------------------------------------------
// Kernel 2: flash attention fp16 — EXACT R14/R16 kernel (passing producer).
// SPLIT-K x2; per-lane lsum; in-loop c-staging; XCD-pinned 1152 grid.
// ---------------------------------------------------------------------------
__global__ __launch_bounds__(256, 4) void attn_f16(
    const h16* __restrict__ qT, const h16* __restrict__ kT,
    const h16* __restrict__ vN, h16* __restrict__ attT,
    h16* __restrict__ pO1, float2* __restrict__ pml)
{
    // bijective on 1152 = 8 XCDs x 144 slots; slot -> (group 0..7, x 0..17)
    const int f    = blockIdx.x;
    const int xcd  = f & 7;
    const int slot = f >> 3;                  // 0..143
    const int grp  = slot / 18;               // 0..7
    const int x    = slot % 18;
    const int bhh  = xcd + 8 * grp;           // 0..63, pinned to XCD f&7
    const int bh   = bhh & 31;
    const int half = bhh >> 5;
    const int b    = bh >> 3;
    const int h    = bh & 7;
    const int s0   = x * 128;

    __shared__ h16 Ks[2][64 * 64];
    __shared__ h16 Vs[2][64 * 64];

    const int tid = threadIdx.x;
    const int lid = tid & 63, w = tid >> 6;   // w = 0..3
    const int l31 = lid & 31, hi = lid >> 5;
    const int srow = lid >> 3;
    const int sblk = (lid & 7) ^ (srow & 7);

    const h16* qb = qT + ((size_t)bh) * S_LEN * 64;
    const h16* kb = kT + ((size_t)bh) * S_LEN * 64;
    const h16* vb = vN + ((size_t)bh) * 64 * S_LEN;

    const int sq = s0 + w * 32 + l31;   // this lane's query row

    // Q B-frags: lane holds Q[sq][d], d = ds*16 + hi*8 + (0..7)
    f16x8 qf[4];
    {
        const h16* qrow = qb + (size_t)sq * 64;
#pragma unroll
        for (int ds = 0; ds < 4; ds++)
            qf[ds] = *(const f16x8*)(qrow + ds * 16 + hi * 8);
    }

    // stage global tile t into buffer buf (4 gll16/wave: 2 K + 2 V chunks)
    auto stage = [&](int t, int buf) {
        const int kt = t * 64;
        for (int c = w; c < 16; c += 4) {
            if (c < 8)
                gll16(kb + (size_t)(kt + c * 8 + srow) * 64 + sblk * 8,
                      &Ks[buf][c * 8 * 64]);
            else
                gll16(vb + (size_t)((c - 8) * 8 + srow) * S_LEN + kt + sblk * 8,
                      &Vs[buf][(c - 8) * 8 * 64]);
        }
    };

    const int t0 = half * 18;   // first global tile for this block
    stage(t0, 0);
    __syncthreads();

    float m_run = -1e30f, l_run = 0.f;
    f32x16 oacc0 = (f32x16)0.f, oacc1 = (f32x16)0.f;

    for (int i = 0; i < 18; i++) {
        const int cur = i & 1;
        if (i + 1 < 18) stage(t0 + i + 1, cur ^ 1);

        const h16* Kc = Ks[cur];
        const h16* Vc = Vs[cur];

        // S^T[t][s]: sacc0 t=0..31, sacc1 t=32..63
        f32x16 sacc0 = (f32x16)0.f, sacc1 = (f32x16)0.f;
#pragma unroll
        for (int ds = 0; ds < 4; ds++) {
            const int bc = 2 * ds + hi;
            {
                const int row = l31;
                f16x8 kf = *(const f16x8*)&Kc[row * 64 + ((bc ^ (row & 7)) * 8)];
                sacc0 = __builtin_amdgcn_mfma_f32_32x32x16_f16(kf, qf[ds], sacc0, 0, 0, 0);
            }
            {
                const int row = 32 + l31;
                f16x8 kf = *(const f16x8*)&Kc[row * 64 + ((bc ^ (row & 7)) * 8)];
                sacc1 = __builtin_amdgcn_mfma_f32_32x32x16_f16(kf, qf[ds], sacc1, 0, 0, 0);
            }
        }

        // column max (max3-fusable triples on two independent chains)
        float ma = sacc0[0], mb2 = sacc1[0];
#pragma unroll
        for (int r = 1; r < 15; r += 2) {
            ma  = fmaxf(fmaxf(ma,  sacc0[r]), sacc0[r + 1]);
            mb2 = fmaxf(fmaxf(mb2, sacc1[r]), sacc1[r + 1]);
        }
        ma  = fmaxf(ma,  sacc0[15]);
        mb2 = fmaxf(mb2, sacc1[15]);
        float mloc = fmaxf(ma, mb2);
        mloc = fmaxf(mloc, __shfl_xor(mloc, 32));

        // defer-max: rescale only when tile max grew past threshold (exp2 dom)
        if (!__all(mloc <= m_run + 8.0f)) {
            const float mnew = fmaxf(m_run, mloc);
            const float resc = fexp2(m_run - mnew);
#pragma unroll
            for (int r = 0; r < 16; r++) { oacc0[r] *= resc; oacc1[r] *= resc; }
            l_run *= resc;
            m_run = mnew;
        }

        // P = exp2(S - m_run) in place; accumulate l per-lane
        float lsum = 0.f;
#pragma unroll
        for (int r = 0; r < 16; r++) {
            sacc0[r] = fexp2(sacc0[r] - m_run); lsum += sacc0[r];
        }
#pragma unroll
        for (int r = 0; r < 16; r++) {
            sacc1[r] = fexp2(sacc1[r] - m_run); lsum += sacc1[r];
        }
        l_run += lsum + __shfl_xor(lsum, 32);

        // pack P into 4 B-frags (t-slices of 16) via cvt_pk + permlane32_swap
        f16x8 pf[4];
#pragma unroll
        for (int j = 0; j < 4; j++) {
            const int bse = (j & 1) * 8;
            float pv[8];
#pragma unroll
            for (int r = 0; r < 8; r++)
                pv[r] = (j < 2) ? sacc0[bse + r] : sacc1[bse + r];
            unsigned X0 = cvtpk(pv[0], pv[1]);
            unsigned X1 = cvtpk(pv[2], pv[3]);
            unsigned Y0 = cvtpk(pv[4], pv[5]);
            unsigned Y1 = cvtpk(pv[6], pv[7]);
            asm("v_permlane32_swap_b32 %0, %1" : "+v"(X0), "+v"(Y0));
            asm("v_permlane32_swap_b32 %0, %1" : "+v"(X1), "+v"(Y1));
            union { unsigned u[4]; f16x8 v; } pkk;
            pkk.u[0] = X0; pkk.u[1] = X1; pkk.u[2] = Y0; pkk.u[3] = Y1;
            pf[j] = pkk.v;
        }

        // O += mfma(Vfrag, Pfrag): out[d][s], d-tiles 0/1
#pragma unroll
        for (int j = 0; j < 4; j++) {
            const int bc = 2 * j + hi;
            {
                const int row = l31;
                f16x8 vf = *(const f16x8*)&Vc[row * 64 + ((bc ^ (row & 7)) * 8)];
                oacc0 = __builtin_amdgcn_mfma_f32_32x32x16_f16(vf, pf[j], oacc0, 0, 0, 0);
            }
            {
                const int row = 32 + l31;
                f16x8 vf = *(const f16x8*)&Vc[row * 64 + ((bc ^ (row & 7)) * 8)];
                oacc1 = __builtin_amdgcn_mfma_f32_32x32x16_f16(vf, pf[j], oacc1, 0, 0, 0);
            }
        }
        __syncthreads();   // next tile staged (vmcnt drain) + Ks/Vs reads done
    }

    // epilogue: normalized partial O/l (fp16) + (m,l) for the combiner
    const float inv = 1.0f / l_run;
    h16* ob = (half ? pO1 : attT) + ((size_t)b * S_LEN + sq) * CDIM + h * 64;
#pragma unroll
    for (int gi = 0; gi < 4; gi++) {
        union { h16 hh[4]; uint2 u; } p0, p1;
#pragma unroll
        for (int r = 0; r < 4; r++) {
            p0.hh[r] = (h16)(oacc0[gi * 4 + r] * inv);
            p1.hh[r] = (h16)(oacc1[gi * 4 + r] * inv);
        }
        *(uint2*)(ob + 8 * gi + 4 * hi)      = p0.u;
        *(uint2*)(ob + 32 + 8 * gi + 4 * hi) = p1.u;
    }
    if (hi == 0)
        pml[(size_t)half * 73728 + (size_t)bh * S_LEN + sq] =
            make_float2(m_run, l_run);
}

// ---------------------------------------------------------------------------
// Kernel 3: output projection, fused split-K merge, NO Xs LDS (fixed units):
// B-fragment K-elements within a 64-step are [kc*32 + g*8 .. +7] (h16), so
// goff = row*CDIM + kt + kc*32 + g*8  (max 448+32+24+7 = 511, in bounds).
// ---------------------------------------------------------------------------
__global__ __launch_bounds__(256) void gemm_out(
    const h16* __restrict__ attT, const h16* __restrict__ pO1,
    const float2* __restrict__ pml, const h16* __restrict__ Wh,
    const float* __restrict__ bout, float* __restrict__ out)
{
    const int n0 = blockIdx.x * 64;
    const int m0 = blockIdx.y * 128;
    const int b  = blockIdx.z;
    __shared__ h16 Ws[128 * 64];
    __shared__ float2 wts[8 * 64];   // [head][row] merge weights

    const int tid = threadIdx.x;
    const int lid = tid & 63, w = tid >> 6;
    const int g = lid >> 4, ln = lid & 15;
    const int wm = w & 1, wn = w >> 1;     // wm: m-half(64), wn: n-half(32)
    const int srow = lid >> 3;
    const int sblk = (lid & 7) ^ (srow & 7);

    // precompute merge weights for all 8 heads x 64 rows of this n-tile
    for (int e = tid; e < 512; e += 256) {
        const int hh = e >> 6, row = e & 63;
        const size_t rr = (size_t)(b * 8 + hh) * S_LEN + (n0 + row);
        const float2 ml0 = pml[rr];
        const float2 ml1 = pml[73728 + rr];
        const float m  = fmaxf(ml0.x, ml1.x);
        const float a0 = fexp2(ml0.x - m) * ml0.y;
        const float a1 = fexp2(ml1.x - m) * ml1.y;
        const float iv = 1.0f / fmaxf(a0 + a1, 1e-20f);
        wts[e] = make_float2(a0 * iv, a1 * iv);
    }

    f32x4 acc[2][4];
#pragma unroll
    for (int i = 0; i < 2; i++)
#pragma unroll
        for (int j = 0; j < 4; j++) acc[i][j] = (f32x4)0.f;

    const h16* Wbase = Wh + (size_t)m0 * CDIM;

    for (int kt = 0; kt < CDIM; kt += 64) {
        __syncthreads();   // Ws reads of prev iter done (also fences wts once)
#pragma unroll
        for (int i = 0; i < 4; i++) {
            const int row0 = w * 32 + i * 8;
            gll16(Wbase + (size_t)(row0 + srow) * CDIM + kt + sblk * 8, &Ws[row0 * 64]);
        }
        __syncthreads();   // Ws staged (vmcnt drain)

        const int hh = kt >> 6;   // this K-step's head
#pragma unroll
        for (int kc = 0; kc < 2; kc++) {
            f16x8 af[4], bf[2];
#pragma unroll
            for (int j = 0; j < 4; j++) {
                const int ra = wm * 64 + j * 16 + ln;
                const int ca = (kc * 64 + g * 16) ^ ((ra & 7) << 4);
                af[j] = *(const f16x8*)&Ws[ra * 64 + ca / 2];
            }
#pragma unroll
            for (int i = 0; i < 2; i++) {
                const int row = wn * 32 + i * 16 + ln;
                const size_t goff = ((size_t)b * S_LEN + n0 + row) * CDIM
                                  + kt + kc * 32 + g * 8;   // ELEMENT offsets
                union { uint4 u; h16 hh8[8]; } x0, x1, o;
                x0.u = *(const uint4*)(attT + goff);
                x1.u = *(const uint4*)(pO1 + goff);
                const float2 wt = wts[hh * 64 + row];
#pragma unroll
                for (int k = 0; k < 8; k++)
                    o.hh8[k] = (h16)(wt.x * (float)x0.hh8[k] +
                                     wt.y * (float)x1.hh8[k]);
                bf[i] = *(f16x8*)&o.hh8[0];
            }
#pragma unroll
            for (int i = 0; i < 2; i++)
#pragma unroll
                for (int j = 0; j < 4; j++)
                    acc[i][j] = __builtin_amdgcn_mfma_f32_16x16x32_f16(
                        bf[i], af[j], acc[i][j], 0, 0, 0);
        }
    }

#pragma unroll
    for (int j = 0; j < 4; j++) {
        const int m = m0 + wm * 64 + j * 16 + ln;
        const float bias = bout[m];
        float* base = out + ((size_t)b * CDIM + m) * S_LEN;
#pragma unroll
        for (int i = 0; i < 2; i++) {
            const int nb = n0 + wn * 32 + i * 16 + 4 * g;
            float4 o;
            o.x = acc[i][j][0] + bias;
            o.y = acc[i][j][1] + bias;
            o.z = acc[i][j][2] + bias;
            o.w = acc[i][j][3] + bias;
            *(float4*)(base + nb) = o;
        }
    }
}

// ---------------------------------------------------------------------------
extern "C" void kernel_launch(void* const* d_in, const int* in_sizes, int n_in,
                              void* d_out, int out_size, void* d_ws, size_t ws_size,
                              hipStream_t stream)
{
    const float* x    = (const float*)d_in[0];
    const float* Wqkv = (const float*)d_in[1];
    const float* bqkv = (const float*)d_in[2];
    const float* Wout = (const float*)d_in[3];
    const float* bout = (const float*)d_in[4];
    float* out = (float*)d_out;

    h16* xT   = (h16*)d_ws;                          // [4][2304][512]; pO1 after qkv
    h16* Wq_h = xT   + (size_t)4 * S_LEN * CDIM;     // [1536][512]; pml after qkv
    h16* Wo_h = Wq_h + (size_t)1536 * 512;           // [512][512]
    h16* qT   = Wo_h + (size_t)512 * 512;            // [4][8][2304][64]
    h16* kT   = qT   + (size_t)4 * 8 * S_LEN * 64;
    h16* vN   = kT   + (size_t)4 * 8 * S_LEN * 64;   // [4][8][64][2304]
    h16* attT = vN   + (size_t)4 * 8 * S_LEN * 64;   // [4][2304][512]

    h16*    pO1 = xT;                                // aliases xT (dead after qkv)
    float2* pml = (float2*)Wq_h;                     // aliases Wq_h (dead after qkv)

    prep    <<<2176,            256, 0, stream>>>(x, xT, Wqkv, Wout, Wq_h, Wo_h);
    gemm_qkv<<<dim3(18, 12, 4), 256, 0, stream>>>(Wq_h, bqkv, xT, qT, kT, vN);
    attn_f16<<<1152,            256, 0, stream>>>(qT, kT, vN, attT, pO1, pml);
    gemm_out<<<dim3(36, 4, 4),  256, 0, stream>>>(attT, pO1, pml, Wo_h, bout, out);
}

// Round 20
// 125.633 us; speedup vs baseline: 1.1292x; 1.1292x over previous
//
#include <hip/hip_runtime.h>

#define S_LEN 2304   // 48*48
#define CDIM  512
#define NHEAD 8

typedef __attribute__((ext_vector_type(4)))  float f32x4;
typedef __attribute__((ext_vector_type(16))) float f32x16;
typedef __attribute__((ext_vector_type(8)))  _Float16 f16x8;
typedef __attribute__((ext_vector_type(2)))  __fp16 fp16x2r;  // cvt_pkrtz native type
typedef _Float16 h16;

// softmax runs in exp2 domain: q pre-scaled by 1/sqrt(64) * log2(e)
#define QSCALE 0.18033688011112042f

__device__ __forceinline__ float fexp2(float x) {
#if __has_builtin(__builtin_amdgcn_exp2f)
    return __builtin_amdgcn_exp2f(x);
#else
    return exp2f(x);
#endif
}

__device__ __forceinline__ unsigned cvtpk(float a, float b) {
    union { fp16x2r v; unsigned u; } c;
    c.v = __builtin_amdgcn_cvt_pkrtz(a, b);
    return c.u;
}

// async global->LDS, 16B per lane; LDS dest = wave-uniform base + lane*16
__device__ __forceinline__ void gll16(const h16* g, h16* l) {
    __builtin_amdgcn_global_load_lds(
        (const __attribute__((address_space(1))) unsigned int*)g,
        (__attribute__((address_space(3))) unsigned int*)l, 16, 0, 0);
}

// ---------------------------------------------------------------------------
// Kernel 0: fused prep. blocks [0,1152): transpose x -> xT fp16;
//           blocks [1152,2176): convert Wqkv/Wout fp32 -> fp16.
// ---------------------------------------------------------------------------
__global__ __launch_bounds__(256) void prep(
    const float* __restrict__ x, h16* __restrict__ xT,
    const float* __restrict__ Wq, const float* __restrict__ Wo,
    h16* __restrict__ Wq_h, h16* __restrict__ Wo_h)
{
    const int bid = blockIdx.x;
    if (bid >= 1152) {
        const int NQ = 1536 * 512;
        const int NO = 512 * 512;
        int i = ((bid - 1152) * 256 + threadIdx.x) * 4;
        if (i >= NQ + NO) return;
        float4 v;
        h16* dst;
        if (i < NQ) { v = *(const float4*)(Wq + i);        dst = Wq_h + i; }
        else        { v = *(const float4*)(Wo + (i - NQ)); dst = Wo_h + (i - NQ); }
        union { h16 h[4]; uint2 u; } pk;
        pk.h[0]=(h16)v.x; pk.h[1]=(h16)v.y; pk.h[2]=(h16)v.z; pk.h[3]=(h16)v.w;
        *(uint2*)dst = pk.u;
        return;
    }
    const int s0 = (bid % 36) * 64;
    const int c0 = ((bid / 36) & 7) * 64;
    const int b  = bid / 288;
    __shared__ h16 Ts[64][76];

    const int t  = threadIdx.x;
    const int cq = t >> 4;
    const int sq = t & 15;

    const float* xb = x + ((size_t)b * CDIM + c0 + cq * 4) * S_LEN + s0 + sq * 4;
    float4 r0 = *(const float4*)(xb);
    float4 r1 = *(const float4*)(xb + S_LEN);
    float4 r2 = *(const float4*)(xb + 2 * S_LEN);
    float4 r3 = *(const float4*)(xb + 3 * S_LEN);

    union { h16 h[4]; uint2 u; } pk;
    pk.h[0]=(h16)r0.x; pk.h[1]=(h16)r1.x; pk.h[2]=(h16)r2.x; pk.h[3]=(h16)r3.x;
    *(uint2*)&Ts[sq*4+0][cq*4] = pk.u;
    pk.h[0]=(h16)r0.y; pk.h[1]=(h16)r1.y; pk.h[2]=(h16)r2.y; pk.h[3]=(h16)r3.y;
    *(uint2*)&Ts[sq*4+1][cq*4] = pk.u;
    pk.h[0]=(h16)r0.z; pk.h[1]=(h16)r1.z; pk.h[2]=(h16)r2.z; pk.h[3]=(h16)r3.z;
    *(uint2*)&Ts[sq*4+2][cq*4] = pk.u;
    pk.h[0]=(h16)r0.w; pk.h[1]=(h16)r1.w; pk.h[2]=(h16)r2.w; pk.h[3]=(h16)r3.w;
    *(uint2*)&Ts[sq*4+3][cq*4] = pk.u;

    __syncthreads();
    const int s  = t >> 2;
    const int cc = (t & 3) * 16;
    uint2 a0 = *(uint2*)&Ts[s][cc + 0];
    uint2 a1 = *(uint2*)&Ts[s][cc + 4];
    uint2 a2 = *(uint2*)&Ts[s][cc + 8];
    uint2 a3 = *(uint2*)&Ts[s][cc + 12];
    h16* dst = xT + ((size_t)b * S_LEN + s0 + s) * CDIM + c0 + cc;
    uint4 w0 = make_uint4(a0.x, a0.y, a1.x, a1.y);
    uint4 w1 = make_uint4(a2.x, a2.y, a3.x, a3.y);
    *(uint4*)dst       = w0;
    *(uint4*)(dst + 8) = w1;
}

// ---------------------------------------------------------------------------
// Kernel 1: QKV projection, fp16 MFMA. q rows get *QSCALE (softmax exp2 domain).
// ---------------------------------------------------------------------------
__global__ __launch_bounds__(256) void gemm_qkv(
    const h16* __restrict__ Wh, const float* __restrict__ bqkv,
    const h16* __restrict__ xT, h16* __restrict__ qT, h16* __restrict__ kT,
    h16* __restrict__ vN)
{
    const int n0 = blockIdx.x * 128;
    const int m0 = blockIdx.y * 128;
    const int b  = blockIdx.z;
    __shared__ h16 Ws[128 * 64];
    __shared__ h16 Xs[128 * 64];

    const int tid = threadIdx.x;
    const int lid = tid & 63, w = tid >> 6;
    const int g = lid >> 4, ln = lid & 15;
    const int wm = w & 1, wn = w >> 1;
    const int srow = lid >> 3;
    const int sblk = (lid & 7) ^ (srow & 7);

    f32x4 acc[4][4];
#pragma unroll
    for (int i = 0; i < 4; i++)
#pragma unroll
        for (int j = 0; j < 4; j++) acc[i][j] = (f32x4)0.f;

    const h16* Wbase = Wh + (size_t)m0 * CDIM;
    const h16* Xbase = xT + ((size_t)b * S_LEN + n0) * CDIM;
    const bool vblk = (m0 >= 1024);

    for (int kt = 0; kt < CDIM; kt += 64) {
        __syncthreads();
#pragma unroll
        for (int i = 0; i < 4; i++) {
            const int row0 = w * 32 + i * 8;
            gll16(Wbase + (size_t)(row0 + srow) * CDIM + kt + sblk * 8, &Ws[row0 * 64]);
            gll16(Xbase + (size_t)(row0 + srow) * CDIM + kt + sblk * 8, &Xs[row0 * 64]);
        }
        __syncthreads();

#pragma unroll
        for (int kc = 0; kc < 2; kc++) {
            f16x8 af[4], bf[4];
#pragma unroll
            for (int i = 0; i < 4; i++) {
                const int ra = wm * 64 + i * 16 + ln;
                const int ca = (kc * 64 + g * 16) ^ ((ra & 7) << 4);
                af[i] = *(const f16x8*)&Ws[ra * 64 + ca / 2];
                const int rb = wn * 64 + i * 16 + ln;
                const int cb = (kc * 64 + g * 16) ^ ((rb & 7) << 4);
                bf[i] = *(const f16x8*)&Xs[rb * 64 + cb / 2];
            }
            if (!vblk) {
#pragma unroll
                for (int i = 0; i < 4; i++)
#pragma unroll
                    for (int j = 0; j < 4; j++)
                        acc[i][j] = __builtin_amdgcn_mfma_f32_16x16x32_f16(
                            af[i], bf[j], acc[i][j], 0, 0, 0);
            } else {
#pragma unroll
                for (int i = 0; i < 4; i++)
#pragma unroll
                    for (int j = 0; j < 4; j++)
                        acc[i][j] = __builtin_amdgcn_mfma_f32_16x16x32_f16(
                            bf[i], af[j], acc[i][j], 0, 0, 0);
            }
        }
    }

    if (!vblk) {
#pragma unroll
        for (int i = 0; i < 4; i++) {
            const int mb = m0 + wm * 64 + i * 16 + 4 * g;
            const float4 bv = *(const float4*)&bqkv[mb];
            const int mloc = mb & 511;
            const int hh = mloc >> 6, d0 = mloc & 63;
            const bool isq = (mb < 512);
            const float scl = isq ? QSCALE : 1.0f;
            h16* base = (isq ? qT : kT);
#pragma unroll
            for (int j = 0; j < 4; j++) {
                const int n = n0 + wn * 64 + j * 16 + ln;
                union { h16 h[4]; uint2 u; } pk;
                pk.h[0] = (h16)((acc[i][j][0] + bv.x) * scl);
                pk.h[1] = (h16)((acc[i][j][1] + bv.y) * scl);
                pk.h[2] = (h16)((acc[i][j][2] + bv.z) * scl);
                pk.h[3] = (h16)((acc[i][j][3] + bv.w) * scl);
                *(uint2*)(base + (((size_t)b * 8 + hh) * S_LEN + n) * 64 + d0) = pk.u;
            }
        }
    } else {
#pragma unroll
        for (int j = 0; j < 4; j++) {
            const int m = m0 + wm * 64 + j * 16 + ln;
            const float bias = bqkv[m];
            const int mloc = m - 1024;
            const int hh = mloc >> 6, d = mloc & 63;
            h16* base = vN + (((size_t)b * 8 + hh) * 64 + d) * S_LEN;
#pragma unroll
            for (int i = 0; i < 4; i++) {
                const int nb = n0 + wn * 64 + i * 16 + 4 * g;
                union { h16 h[4]; uint2 u; } pk;
                pk.h[0] = (h16)(acc[i][j][0] + bias);
                pk.h[1] = (h16)(acc[i][j][1] + bias);
                pk.h[2] = (h16)(acc[i][j][2] + bias);
                pk.h[3] = (h16)(acc[i][j][3] + bias);
                *(uint2*)(base + nb) = pk.u;
            }
        }
    }
}

// ---------------------------------------------------------------------------
// Kernel 2: flash attention fp16 — R14-exact inner loop (per-lane lsum),
// SPLIT-K x3: each block handles 12 of the 36 K-tiles.
//  - 1728 blocks = 6912 waves = 6.75 waves/SIMD (was 4.5 at split x2).
//  - XCD-pinned: 1728 = 8 XCD x (12 (bh,half) groups x 18 s-blocks); all 3
//    halves of a bh land on one XCD (disjoint K-thirds, 2.4 MB per L2).
//  - partial O fp16 to attT / pO1 / pO2 by half; (m,l) float2 to pml[half].
// ---------------------------------------------------------------------------
__global__ __launch_bounds__(256, 4) void attn_f16(
    const h16* __restrict__ qT, const h16* __restrict__ kT,
    const h16* __restrict__ vN, h16* __restrict__ attT,
    h16* __restrict__ pO1, h16* __restrict__ pO2, float2* __restrict__ pml)
{
    // bijective on 1728 = 8 XCDs x 216 slots; slot -> (group 0..11, x 0..17)
    const int f    = blockIdx.x;
    const int xcd  = f & 7;
    const int slot = f >> 3;                  // 0..215
    const int grp  = slot / 18;               // 0..11
    const int x    = slot % 18;
    const int bhh  = xcd + 8 * grp;           // 0..95, pinned to XCD f&7
    const int bh   = bhh & 31;
    const int half = bhh >> 5;                // 0..2
    const int b    = bh >> 3;
    const int h    = bh & 7;
    const int s0   = x * 128;

    __shared__ h16 Ks[2][64 * 64];
    __shared__ h16 Vs[2][64 * 64];

    const int tid = threadIdx.x;
    const int lid = tid & 63, w = tid >> 6;   // w = 0..3
    const int l31 = lid & 31, hi = lid >> 5;
    const int srow = lid >> 3;
    const int sblk = (lid & 7) ^ (srow & 7);

    const h16* qb = qT + ((size_t)bh) * S_LEN * 64;
    const h16* kb = kT + ((size_t)bh) * S_LEN * 64;
    const h16* vb = vN + ((size_t)bh) * 64 * S_LEN;

    const int sq = s0 + w * 32 + l31;   // this lane's query row

    // Q B-frags: lane holds Q[sq][d], d = ds*16 + hi*8 + (0..7)
    f16x8 qf[4];
    {
        const h16* qrow = qb + (size_t)sq * 64;
#pragma unroll
        for (int ds = 0; ds < 4; ds++)
            qf[ds] = *(const f16x8*)(qrow + ds * 16 + hi * 8);
    }

    // stage global tile t into buffer buf (4 gll16/wave: 2 K + 2 V chunks)
    auto stage = [&](int t, int buf) {
        const int kt = t * 64;
        for (int c = w; c < 16; c += 4) {
            if (c < 8)
                gll16(kb + (size_t)(kt + c * 8 + srow) * 64 + sblk * 8,
                      &Ks[buf][c * 8 * 64]);
            else
                gll16(vb + (size_t)((c - 8) * 8 + srow) * S_LEN + kt + sblk * 8,
                      &Vs[buf][(c - 8) * 8 * 64]);
        }
    };

    const int t0 = half * 12;   // first global tile for this block
    stage(t0, 0);
    __syncthreads();

    float m_run = -1e30f, l_run = 0.f;
    f32x16 oacc0 = (f32x16)0.f, oacc1 = (f32x16)0.f;

    for (int i = 0; i < 12; i++) {
        const int cur = i & 1;
        if (i + 1 < 12) stage(t0 + i + 1, cur ^ 1);

        const h16* Kc = Ks[cur];
        const h16* Vc = Vs[cur];

        // S^T[t][s]: sacc0 t=0..31, sacc1 t=32..63
        f32x16 sacc0 = (f32x16)0.f, sacc1 = (f32x16)0.f;
#pragma unroll
        for (int ds = 0; ds < 4; ds++) {
            const int bc = 2 * ds + hi;
            {
                const int row = l31;
                f16x8 kf = *(const f16x8*)&Kc[row * 64 + ((bc ^ (row & 7)) * 8)];
                sacc0 = __builtin_amdgcn_mfma_f32_32x32x16_f16(kf, qf[ds], sacc0, 0, 0, 0);
            }
            {
                const int row = 32 + l31;
                f16x8 kf = *(const f16x8*)&Kc[row * 64 + ((bc ^ (row & 7)) * 8)];
                sacc1 = __builtin_amdgcn_mfma_f32_32x32x16_f16(kf, qf[ds], sacc1, 0, 0, 0);
            }
        }

        // column max (max3-fusable triples on two independent chains)
        float ma = sacc0[0], mb2 = sacc1[0];
#pragma unroll
        for (int r = 1; r < 15; r += 2) {
            ma  = fmaxf(fmaxf(ma,  sacc0[r]), sacc0[r + 1]);
            mb2 = fmaxf(fmaxf(mb2, sacc1[r]), sacc1[r + 1]);
        }
        ma  = fmaxf(ma,  sacc0[15]);
        mb2 = fmaxf(mb2, sacc1[15]);
        float mloc = fmaxf(ma, mb2);
        mloc = fmaxf(mloc, __shfl_xor(mloc, 32));

        // defer-max: rescale only when tile max grew past threshold (exp2 dom)
        if (!__all(mloc <= m_run + 8.0f)) {
            const float mnew = fmaxf(m_run, mloc);
            const float resc = fexp2(m_run - mnew);
#pragma unroll
            for (int r = 0; r < 16; r++) { oacc0[r] *= resc; oacc1[r] *= resc; }
            l_run *= resc;
            m_run = mnew;
        }

        // P = exp2(S - m_run) in place; accumulate l per-lane
        float lsum = 0.f;
#pragma unroll
        for (int r = 0; r < 16; r++) {
            sacc0[r] = fexp2(sacc0[r] - m_run); lsum += sacc0[r];
        }
#pragma unroll
        for (int r = 0; r < 16; r++) {
            sacc1[r] = fexp2(sacc1[r] - m_run); lsum += sacc1[r];
        }
        l_run += lsum + __shfl_xor(lsum, 32);

        // pack P into 4 B-frags (t-slices of 16) via cvt_pk + permlane32_swap
        f16x8 pf[4];
#pragma unroll
        for (int j = 0; j < 4; j++) {
            const int bse = (j & 1) * 8;
            float pv[8];
#pragma unroll
            for (int r = 0; r < 8; r++)
                pv[r] = (j < 2) ? sacc0[bse + r] : sacc1[bse + r];
            unsigned X0 = cvtpk(pv[0], pv[1]);
            unsigned X1 = cvtpk(pv[2], pv[3]);
            unsigned Y0 = cvtpk(pv[4], pv[5]);
            unsigned Y1 = cvtpk(pv[6], pv[7]);
            asm("v_permlane32_swap_b32 %0, %1" : "+v"(X0), "+v"(Y0));
            asm("v_permlane32_swap_b32 %0, %1" : "+v"(X1), "+v"(Y1));
            union { unsigned u[4]; f16x8 v; } pkk;
            pkk.u[0] = X0; pkk.u[1] = X1; pkk.u[2] = Y0; pkk.u[3] = Y1;
            pf[j] = pkk.v;
        }

        // O += mfma(Vfrag, Pfrag): out[d][s], d-tiles 0/1
#pragma unroll
        for (int j = 0; j < 4; j++) {
            const int bc = 2 * j + hi;
            {
                const int row = l31;
                f16x8 vf = *(const f16x8*)&Vc[row * 64 + ((bc ^ (row & 7)) * 8)];
                oacc0 = __builtin_amdgcn_mfma_f32_32x32x16_f16(vf, pf[j], oacc0, 0, 0, 0);
            }
            {
                const int row = 32 + l31;
                f16x8 vf = *(const f16x8*)&Vc[row * 64 + ((bc ^ (row & 7)) * 8)];
                oacc1 = __builtin_amdgcn_mfma_f32_32x32x16_f16(vf, pf[j], oacc1, 0, 0, 0);
            }
        }
        __syncthreads();   // next tile staged (vmcnt drain) + Ks/Vs reads done
    }

    // epilogue: normalized partial O/l (fp16) + (m,l) for the combiner
    const float inv = 1.0f / l_run;
    h16* obase = (half == 0) ? attT : (half == 1 ? pO1 : pO2);
    h16* ob = obase + ((size_t)b * S_LEN + sq) * CDIM + h * 64;
#pragma unroll
    for (int gi = 0; gi < 4; gi++) {
        union { h16 hh[4]; uint2 u; } p0, p1;
#pragma unroll
        for (int r = 0; r < 4; r++) {
            p0.hh[r] = (h16)(oacc0[gi * 4 + r] * inv);
            p1.hh[r] = (h16)(oacc1[gi * 4 + r] * inv);
        }
        *(uint2*)(ob + 8 * gi + 4 * hi)      = p0.u;
        *(uint2*)(ob + 32 + 8 * gi + 4 * hi) = p1.u;
    }
    if (hi == 0)
        pml[(size_t)half * 73728 + (size_t)bh * S_LEN + sq] =
            make_float2(m_run, l_run);
}

// ---------------------------------------------------------------------------
// Kernel 3: output projection with FUSED 3-way split-K merge (R16 structure).
// LDS-staged Xs = w0*O0 + w1*O1 + w2*O2, swizzled ds_write; eps-guarded.
// ---------------------------------------------------------------------------
__global__ __launch_bounds__(256) void gemm_out(
    const h16* __restrict__ attT, const h16* __restrict__ pO1,
    const h16* __restrict__ pO2, const float2* __restrict__ pml,
    const h16* __restrict__ Wh, const float* __restrict__ bout,
    float* __restrict__ out)
{
    const int n0 = blockIdx.x * 64;
    const int m0 = blockIdx.y * 128;
    const int b  = blockIdx.z;
    __shared__ h16 Ws[128 * 64];
    __shared__ h16 Xs[64 * 64];
    __shared__ float4 wts[8 * 64];   // [head][row] merge weights (x,y,z)

    const int tid = threadIdx.x;
    const int lid = tid & 63, w = tid >> 6;
    const int g = lid >> 4, ln = lid & 15;
    const int wm = w & 1, wn = w >> 1;     // wm: m-half(64), wn: n-half(32)
    const int srow = lid >> 3;
    const int sblk = (lid & 7) ^ (srow & 7);

    // precompute merge weights for all 8 heads x 64 rows of this n-tile
    for (int e = tid; e < 512; e += 256) {
        const int hh = e >> 6, row = e & 63;
        const size_t rr = (size_t)(b * 8 + hh) * S_LEN + (n0 + row);
        const float2 ml0 = pml[rr];
        const float2 ml1 = pml[73728 + rr];
        const float2 ml2 = pml[147456 + rr];
        const float m  = fmaxf(fmaxf(ml0.x, ml1.x), ml2.x);
        const float a0 = fexp2(ml0.x - m) * ml0.y;
        const float a1 = fexp2(ml1.x - m) * ml1.y;
        const float a2 = fexp2(ml2.x - m) * ml2.y;
        const float iv = 1.0f / fmaxf(a0 + a1 + a2, 1e-20f);   // NaN-proof
        wts[e] = make_float4(a0 * iv, a1 * iv, a2 * iv, 0.f);
    }

    f32x4 acc[2][4];
#pragma unroll
    for (int i = 0; i < 2; i++)
#pragma unroll
        for (int j = 0; j < 4; j++) acc[i][j] = (f32x4)0.f;

    const h16* Wbase = Wh + (size_t)m0 * CDIM;

    for (int kt = 0; kt < CDIM; kt += 64) {
        __syncthreads();   // fences wts (first iter) + prev iter's LDS reads
#pragma unroll
        for (int i = 0; i < 4; i++) {
            const int row0 = w * 32 + i * 8;
            gll16(Wbase + (size_t)(row0 + srow) * CDIM + kt + sblk * 8, &Ws[row0 * 64]);
        }
        // Xs = w0*O0 + w1*O1 + w2*O2, reg-staged, swizzled write. 512 chunks.
        const int hh = kt >> 6;   // this K-step's head
#pragma unroll
        for (int p = 0; p < 2; p++) {
            const int idx = tid + p * 256;
            const int row = idx >> 3;
            const int cb  = idx & 7;
            const size_t goff = ((size_t)b * S_LEN + n0 + row) * CDIM + kt + cb * 8;
            union { uint4 u; h16 hh8[8]; } x0, x1, x2, o;
            x0.u = *(const uint4*)(attT + goff);
            x1.u = *(const uint4*)(pO1 + goff);
            x2.u = *(const uint4*)(pO2 + goff);
            const float4 wt = wts[hh * 64 + row];
#pragma unroll
            for (int k = 0; k < 8; k++)
                o.hh8[k] = (h16)(wt.x * (float)x0.hh8[k] +
                                 wt.y * (float)x1.hh8[k] +
                                 wt.z * (float)x2.hh8[k]);
            *(uint4*)&Xs[row * 64 + ((cb ^ (row & 7)) * 8)] = o.u;
        }
        __syncthreads();

#pragma unroll
        for (int kc = 0; kc < 2; kc++) {
            f16x8 af[4], bf[2];
#pragma unroll
            for (int j = 0; j < 4; j++) {
                const int ra = wm * 64 + j * 16 + ln;
                const int ca = (kc * 64 + g * 16) ^ ((ra & 7) << 4);
                af[j] = *(const f16x8*)&Ws[ra * 64 + ca / 2];
            }
#pragma unroll
            for (int i = 0; i < 2; i++) {
                const int rb = wn * 32 + i * 16 + ln;
                const int cb = (kc * 64 + g * 16) ^ ((rb & 7) << 4);
                bf[i] = *(const f16x8*)&Xs[rb * 64 + cb / 2];
            }
#pragma unroll
            for (int i = 0; i < 2; i++)
#pragma unroll
                for (int j = 0; j < 4; j++)
                    acc[i][j] = __builtin_amdgcn_mfma_f32_16x16x32_f16(
                        bf[i], af[j], acc[i][j], 0, 0, 0);
        }
    }

#pragma unroll
    for (int j = 0; j < 4; j++) {
        const int m = m0 + wm * 64 + j * 16 + ln;
        const float bias = bout[m];
        float* base = out + ((size_t)b * CDIM + m) * S_LEN;
#pragma unroll
        for (int i = 0; i < 2; i++) {
            const int nb = n0 + wn * 32 + i * 16 + 4 * g;
            float4 o;
            o.x = acc[i][j][0] + bias;
            o.y = acc[i][j][1] + bias;
            o.z = acc[i][j][2] + bias;
            o.w = acc[i][j][3] + bias;
            *(float4*)(base + nb) = o;
        }
    }
}

// ---------------------------------------------------------------------------
extern "C" void kernel_launch(void* const* d_in, const int* in_sizes, int n_in,
                              void* d_out, int out_size, void* d_ws, size_t ws_size,
                              hipStream_t stream)
{
    const float* x    = (const float*)d_in[0];
    const float* Wqkv = (const float*)d_in[1];
    const float* bqkv = (const float*)d_in[2];
    const float* Wout = (const float*)d_in[3];
    const float* bout = (const float*)d_in[4];
    float* out = (float*)d_out;

    h16* xT   = (h16*)d_ws;                          // [4][2304][512]; pO1 after qkv
    h16* Wq_h = xT   + (size_t)4 * S_LEN * CDIM;     // [1536][512]
    h16* Wo_h = Wq_h + (size_t)1536 * 512;           // [512][512]
    h16* qT   = Wo_h + (size_t)512 * 512;            // [4][8][2304][64]
    h16* kT   = qT   + (size_t)4 * 8 * S_LEN * 64;
    h16* vN   = kT   + (size_t)4 * 8 * S_LEN * 64;   // [4][8][64][2304]
    h16* attT = vN   + (size_t)4 * 8 * S_LEN * 64;   // [4][2304][512]
    h16* pO2  = attT + (size_t)4 * S_LEN * CDIM;     // [4][2304][512] (fresh)
    float2* pml = (float2*)(pO2 + (size_t)4 * S_LEN * CDIM);  // [3][32][2304]

    h16* pO1 = xT;                                   // aliases xT (dead after qkv)

    prep    <<<2176,            256, 0, stream>>>(x, xT, Wqkv, Wout, Wq_h, Wo_h);
    gemm_qkv<<<dim3(18, 12, 4), 256, 0, stream>>>(Wq_h, bqkv, xT, qT, kT, vN);
    attn_f16<<<1728,            256, 0, stream>>>(qT, kT, vN, attT, pO1, pO2, pml);
    gemm_out<<<dim3(36, 4, 4),  256, 0, stream>>>(attT, pO1, pO2, pml, Wo_h, bout, out);
}